// Round 17
// baseline (70.016 us; speedup 1.0000x reference)
//
#include <hip/hip_runtime.h>

#define TT 1024
#define LL 64
#define BB 256
#define KK 32               // class-B piece length
#define WARM 8              // warm-up steps (contraction <= 0.462/step)
#define P0LEN (KK + WARM)   // piece-0 length (40) -> uniform NSTEP for all
#define NSTEP (KK + WARM)   // batched steps per MFMA wave
#define MAXPF 7936          // max full pieces = 256 * 31
#define MF_BLOCKS 124       // 496 waves * 16 chains = 7936
#define SC_BLOCKS 64        // 256 scalar tail waves
#define LOG2E 1.44269504088896340736f
#define LN2   0.69314718055994530942f

typedef __fp16 h2 __attribute__((ext_vector_type(2)));
typedef __fp16 h8 __attribute__((ext_vector_type(8)));
typedef float  f4 __attribute__((ext_vector_type(4)));

__device__ __forceinline__ int h2i(h2 x) { union { h2 h; int i; } u; u.h = x; return u.i; }
__device__ __forceinline__ h2 i2h(int x) { union { int i; h2 h; } u; u.i = x; return u.h; }
union H8 { int w[4]; h8 h; };

// meta[0..256] = prefix of full-piece counts; meta[256] = Pf
__global__ __launch_bounds__(256) void crf_prefix_kernel(
    const int* __restrict__ seq_lens, int* __restrict__ meta)
{
    __shared__ int sbuf[BB];
    const int tid = threadIdx.x;
    const int sl = seq_lens[tid];
    const int work = sl - 1;
    sbuf[tid] = (work >= P0LEN) ? (1 + (work - P0LEN) / KK) : 0;
    __syncthreads();
    for (int off = 1; off < BB; off <<= 1) {
        int v = (tid >= off) ? sbuf[tid - off] : 0;
        __syncthreads();
        sbuf[tid] += v;
        __syncthreads();
    }
    meta[tid + 1] = sbuf[tid];
    if (tid == 0) meta[0] = 0;
}

__global__ __launch_bounds__(256) void crf_main_kernel(
    const float* __restrict__ logits,    // [B][T][L]
    const int*   __restrict__ labels,    // [B][T]
    const int*   __restrict__ seq_lens,  // [B]
    const float* __restrict__ trans,     // [L][L]
    const int*   __restrict__ meta,      // [257]
    float*       __restrict__ part)      // [MAXPF + BB]
{
    __shared__ float uls[4][16][68];     // per-wave U transpose buffer (padded)
    const int tid  = threadIdx.x;
    const int lane = tid & 63;
    const int wv   = tid >> 6;
    const int l15  = lane & 15;
    const int lg4  = lane >> 4;

    if ((int)blockIdx.x < MF_BLOCKS) {
        // ================= MFMA path: 16 chains per wave =================
        const int wid = blockIdx.x * 4 + wv;
        const int Pf  = meta[BB];

        // ---- B-fragments of E = exp(trans): tiles nt (cols), chunks kc (k) ----
        // k-map (ours, consistent A&B): k = kc*32 + 8*lg4 + 2*rp + h
        H8 bf[4][2];
        #pragma unroll
        for (int nt = 0; nt < 4; ++nt)
            #pragma unroll
            for (int kc = 0; kc < 2; ++kc)
                #pragma unroll
                for (int rp = 0; rp < 4; ++rp) {
                    int k0  = kc * 32 + 8 * lg4 + 2 * rp;
                    int colE = 16 * nt + l15;
                    float e0 = __builtin_amdgcn_exp2f(trans[k0 * LL + colE] * LOG2E);
                    float e1 = __builtin_amdgcn_exp2f(trans[(k0 + 1) * LL + colE] * LOG2E);
                    bf[nt][kc].w[rp] = h2i(__builtin_amdgcn_cvt_pkrtz(e0, e1));
                }

        // ---- per-chain setup: chain c lives at rows 4*lg4+j (j=c&3, grp=c>>2) ----
        float scR[4] = {0.f, 0.f, 0.f, 0.f};
        float AinR[4] = {0.f, 0.f, 0.f, 0.f};
        int   pidR[4] = {0, 0, 0, 0};
        int   actR[4] = {0, 0, 0, 0};
        int   p0R[4]  = {0, 0, 0, 0};
        const float* pR[4];
        #pragma unroll
        for (int j = 0; j < 4; ++j) pR[j] = logits + l15 + LL;  // safe default (row 1)

        #pragma unroll
        for (int c = 0; c < 16; ++c) {
            const int j = c & 3;
            const int cid = 16 * wid + c;
            const bool act = (cid < Pf);
            int b = 0, idx = 0;
            if (act) {
                int blo = 0, bhi = BB;
                while (bhi - blo > 1) {
                    int mid = (blo + bhi) >> 1;
                    if (meta[mid] <= cid) blo = mid; else bhi = mid;
                }
                b = blo;
                idx = cid - meta[b];
            }
            const bool p0 = (idx == 0);
            const int start = (!act) ? 1 : (p0 ? 1 : (1 + P0LEN + (idx - 1) * KK - WARM));
            const int lo    = p0 ? 1 : (start + WARM);
            const int units = p0 ? P0LEN : KK;
            const float* lgp = logits + (size_t)b * TT * LL;
            const int*   lab = labels + b * TT;
            float sc = 0.f;
            if (act) {
                int t0 = lo + lane;
                if (lane < units) {
                    int l1 = lab[t0];
                    sc = lgp[(size_t)t0 * LL + l1] + trans[lab[t0 - 1] * LL + l1];
                }
                if (p0 && lane == 0) sc += lgp[lab[0]];
                #pragma unroll
                for (int off = 32; off; off >>= 1) sc += __shfl_xor(sc, off, 64);
            }
            const bool sel = (lg4 == (c >> 2));
            scR[j]  = sel ? sc : scR[j];
            pidR[j] = sel ? cid : pidR[j];
            actR[j] = sel ? (act ? 1 : 0) : actR[j];
            p0R[j]  = sel ? (p0 ? 1 : 0) : p0R[j];
            const float* np = lgp + (size_t)start * LL + l15;
            pR[j] = sel ? np : pR[j];
        }

        // ---- init U rows: u(start-1) = exp(logit[start-1][state]) ----
        #pragma unroll
        for (int j = 0; j < 4; ++j)
            #pragma unroll
            for (int nt = 0; nt < 4; ++nt)
                uls[wv][4 * lg4 + j][16 * nt + l15] =
                    __builtin_amdgcn_exp2f(pR[j][16 * nt - LL] * LOG2E);

        // g prefetch for n=0 (row start)
        float gA[4][4], gB[4][4];
        #pragma unroll
        for (int j = 0; j < 4; ++j) {
            #pragma unroll
            for (int nt = 0; nt < 4; ++nt) gA[j][nt] = pR[j][16 * nt];
            pR[j] += LL;
        }

        int C = 0;
        float u2[4][4];

        for (int n = 0; n < NSTEP; ++n) {
            // A-fragments from LDS (u at t-1), our k-map: k = kc*32 + 8*lg4 + e
            H8 af[2];
            #pragma unroll
            for (int kc = 0; kc < 2; ++kc) {
                const float* lp = &uls[wv][l15][kc * 32 + 8 * lg4];
                f4 x0 = *(const f4*)lp;
                f4 x1 = *(const f4*)(lp + 4);
                af[kc].w[0] = h2i(__builtin_amdgcn_cvt_pkrtz(x0[0], x0[1]));
                af[kc].w[1] = h2i(__builtin_amdgcn_cvt_pkrtz(x0[2], x0[3]));
                af[kc].w[2] = h2i(__builtin_amdgcn_cvt_pkrtz(x1[0], x1[1]));
                af[kc].w[3] = h2i(__builtin_amdgcn_cvt_pkrtz(x1[2], x1[3]));
            }
            // prefetch next g row
            #pragma unroll
            for (int j = 0; j < 4; ++j) {
                #pragma unroll
                for (int nt = 0; nt < 4; ++nt) gB[j][nt] = pR[j][16 * nt];
                pR[j] += LL;
            }
            // P = U * E
            f4 acc[4];
            #pragma unroll
            for (int nt = 0; nt < 4; ++nt) {
                f4 z = {0.f, 0.f, 0.f, 0.f};
                z = __builtin_amdgcn_mfma_f32_16x16x32_f16(af[0].h, bf[nt][0].h, z, 0, 0, 0);
                z = __builtin_amdgcn_mfma_f32_16x16x32_f16(af[1].h, bf[nt][1].h, z, 0, 0, 0);
                acc[nt] = z;
            }
            // apply g; D elem (nt, j) = chain 4*lg4+j, state 16*nt+l15
            #pragma unroll
            for (int nt = 0; nt < 4; ++nt)
                #pragma unroll
                for (int j = 0; j < 4; ++j)
                    u2[nt][j] = acc[nt][j] * __builtin_amdgcn_exp2f(gA[j][nt] * LOG2E);
            // wave-uniform renorm: ref = lane0 elem (chain 0, state 0); target 2^-2
            int eb = (__builtin_amdgcn_readfirstlane(__float_as_int(u2[0][0])) >> 23) & 0xFF;
            C += eb - 125;
            float scl = __int_as_float((252 - eb) << 23);
            #pragma unroll
            for (int nt = 0; nt < 4; ++nt)
                #pragma unroll
                for (int j = 0; j < 4; ++j)
                    u2[nt][j] = fminf(u2[nt][j] * scl, 60000.f);
            // A_in measure (class-B) at n == WARM-1
            if (n == WARM - 1) {
                #pragma unroll
                for (int j = 0; j < 4; ++j) {
                    float s = (u2[0][j] + u2[1][j]) + (u2[2][j] + u2[3][j]);
                    s += __shfl_xor(s, 1, 64);
                    s += __shfl_xor(s, 2, 64);
                    s += __shfl_xor(s, 4, 64);
                    s += __shfl_xor(s, 8, 64);
                    float A = ((float)C + __builtin_amdgcn_logf(fmaxf(s, 1e-30f))) * LN2;
                    AinR[j] = p0R[j] ? 0.f : A;
                }
            }
            // write back U for next step
            #pragma unroll
            for (int nt = 0; nt < 4; ++nt)
                #pragma unroll
                for (int j = 0; j < 4; ++j)
                    uls[wv][4 * lg4 + j][16 * nt + l15] = u2[nt][j];
            // rotate g
            #pragma unroll
            for (int j = 0; j < 4; ++j)
                #pragma unroll
                for (int nt = 0; nt < 4; ++nt) gA[j][nt] = gB[j][nt];
        }

        // ---- final measure + store ----
        float resR[4];
        #pragma unroll
        for (int j = 0; j < 4; ++j) {
            float s = (u2[0][j] + u2[1][j]) + (u2[2][j] + u2[3][j]);
            s += __shfl_xor(s, 1, 64);
            s += __shfl_xor(s, 2, 64);
            s += __shfl_xor(s, 4, 64);
            s += __shfl_xor(s, 8, 64);
            float Aout = ((float)C + __builtin_amdgcn_logf(fmaxf(s, 1e-30f))) * LN2;
            float r = (Aout - AinR[j]) - scR[j];
            resR[j] = actR[j] ? r : 0.f;
        }
        if (l15 == 0) {
            #pragma unroll
            for (int j = 0; j < 4; ++j) part[pidR[j]] = resR[j];
        }
    } else {
        // ================= scalar tail path: 1 seq per wave =================
        const int b = ((int)blockIdx.x - MF_BLOCKS) * 4 + wv;   // 0..255
        const int slen = seq_lens[b];
        const int work = slen - 1;
        const int nfull = meta[b + 1] - meta[b];
        const int covered = nfull ? (P0LEN + (nfull - 1) * KK) : 0;
        const int lo = 1 + covered;
        const int hi = slen;
        const float* lg  = logits + (size_t)b * TT * LL;
        const int*   lab = labels + b * TT;
        (void)work;

        // E pairs along i for column j = lane
        int ej[32];
        #pragma unroll
        for (int m = 0; m < 32; ++m) {
            float e0 = __builtin_amdgcn_exp2f(trans[(2 * m)     * LL + lane] * LOG2E);
            float e1 = __builtin_amdgcn_exp2f(trans[(2 * m + 1) * LL + lane] * LOG2E);
            ej[m] = h2i(__builtin_amdgcn_cvt_pkrtz(e0, e1));
        }

        float sc = 0.f;
        {
            int units = hi - lo;               // < 40
            int t0 = lo + lane;
            if (lane < units) {
                int l1 = lab[t0];
                sc = lg[(size_t)t0 * LL + l1] + trans[lab[t0 - 1] * LL + l1];
            }
            if (lo == 1 && lane == 0) sc += lg[lab[0]];
            #pragma unroll
            for (int off = 32; off; off >>= 1) sc += __shfl_xor(sc, off, 64);
        }

        const int start = (lo - WARM > 1) ? (lo - WARM) : 1;
        const int lo1   = (lo > 1) ? (lo - 1) : -1;
        const float* col = lg + lane;
        int C = 0, upk;
        float u;

#define RENORM(V) { \
    int eb_ = (__builtin_amdgcn_readfirstlane(__float_as_int(V)) >> 23) & 0xFF; \
    C += eb_ - 127; \
    float scl_ = __int_as_float((254 - eb_) << 23); \
    u = (V) * scl_; \
}
#define PACKD() { \
    float un_ = __shfl_xor(u, 1, 64); \
    upk = h2i(__builtin_amdgcn_cvt_pkrtz(u, un_)); \
}
#define MEAS(OUT) { \
    float us_ = u; \
    _Pragma("unroll") \
    for (int off_ = 32; off_; off_ >>= 1) us_ += __shfl_xor(us_, off_, 64); \
    OUT = ((float)C + __builtin_amdgcn_logf(us_)) * LN2; \
}
        {
            float v0 = __builtin_amdgcn_exp2f(col[(size_t)(start - 1) * LL] * LOG2E);
            RENORM(v0);
            PACKD();
        }
        float A_in = 0.f, A_out;

#define PLD(I) ((size_t)(((start + I) < TT) ? (start + I) : (TT - 1)) * LL)
        float fR0 = col[PLD(0)];
        float fR1 = col[PLD(1)];
        float fR2 = col[PLD(2)];
        float fR3 = col[PLD(3)];
        float fR4 = col[PLD(4)];
        float fR5 = col[PLD(5)];
        float fR6 = col[PLD(6)];
        float fR7 = col[PLD(7)];

#define SC_STEP(I) do { \
    if (t < hi) { \
        float g_ = __builtin_amdgcn_exp2f(fR##I * LOG2E); \
        int nr_ = t + 8; nr_ = (nr_ < TT) ? nr_ : (TT - 1); \
        fR##I = col[(size_t)nr_ * LL]; \
        float a1_ = 0.f, a2_ = 0.f, a3_ = 0.f, a4_ = 0.f; \
        _Pragma("unroll") \
        for (int m_ = 0; m_ < 32; m_ += 4) { \
            int q0_ = __builtin_amdgcn_readlane(upk, 2 * m_); \
            int q1_ = __builtin_amdgcn_readlane(upk, 2 * m_ + 2); \
            int q2_ = __builtin_amdgcn_readlane(upk, 2 * m_ + 4); \
            int q3_ = __builtin_amdgcn_readlane(upk, 2 * m_ + 6); \
            a1_ = __builtin_amdgcn_fdot2(i2h(q0_), i2h(ej[m_]),     a1_, false); \
            a2_ = __builtin_amdgcn_fdot2(i2h(q1_), i2h(ej[m_ + 1]), a2_, false); \
            a3_ = __builtin_amdgcn_fdot2(i2h(q2_), i2h(ej[m_ + 2]), a3_, false); \
            a4_ = __builtin_amdgcn_fdot2(i2h(q3_), i2h(ej[m_ + 3]), a4_, false); \
        } \
        float v_ = ((a1_ + a2_) + (a3_ + a4_)) * g_; \
        RENORM(v_); \
        PACKD(); \
        if (t == lo1) MEAS(A_in); \
        ++t; \
    } \
} while (0)

        int t = start;
        while (t < hi) {
            SC_STEP(0); SC_STEP(1); SC_STEP(2); SC_STEP(3);
            SC_STEP(4); SC_STEP(5); SC_STEP(6); SC_STEP(7);
        }
        MEAS(A_out);
        if (lane == 0) part[MAXPF + b] = (A_out - A_in) - sc;
    }
}

__global__ __launch_bounds__(1024) void reduce_kernel(
    const float* __restrict__ part, float* __restrict__ out)
{
    int tid = threadIdx.x;
    float v = 0.f;
    #pragma unroll
    for (int i = 0; i < 8; ++i) v += part[tid + 1024 * i];
    #pragma unroll
    for (int off = 32; off; off >>= 1) v += __shfl_xor(v, off, 64);
    __shared__ float r[16];
    if ((tid & 63) == 0) r[tid >> 6] = v;
    __syncthreads();
    if (tid == 0) {
        float s = 0.f;
        #pragma unroll
        for (int i = 0; i < 16; ++i) s += r[i];
        out[0] = s;
    }
}

extern "C" void kernel_launch(void* const* d_in, const int* in_sizes, int n_in,
                              void* d_out, int out_size, void* d_ws, size_t ws_size,
                              hipStream_t stream) {
    const float* logits   = (const float*)d_in[0];
    const int*   labels   = (const int*)d_in[1];
    const int*   seq_lens = (const int*)d_in[2];
    const float* trans    = (const float*)d_in[3];

    int*   meta = (int*)d_ws;                         // 257 ints
    float* part = (float*)((char*)d_ws + 4096);       // MAXPF + 256 floats

    crf_prefix_kernel<<<1, 256, 0, stream>>>(seq_lens, meta);
    crf_main_kernel<<<MF_BLOCKS + SC_BLOCKS, 256, 0, stream>>>(
        logits, labels, seq_lens, trans, meta, part);
    reduce_kernel<<<1, 1024, 0, stream>>>(part, (float*)d_out);
}

// Round 19
// 47.727 us; speedup vs baseline: 1.4670x; 1.4670x over previous
//
#include <hip/hip_runtime.h>

#define TT 1024
#define LL 64
#define BB 256             // batch
#define WARM 8             // warm-up steps per piece (contraction <= 0.462/step)
#define NWAVES 4096        // main-kernel waves (1024 blocks x 4)
#define LOG2E 1.44269504088896340736f
#define LN2   0.69314718055994530942f

typedef __fp16 h2 __attribute__((ext_vector_type(2)));
__device__ __forceinline__ h2  i2h(int x) { union { int i; h2 h; } u; u.i = x; return u.h; }
__device__ __forceinline__ int h2i(h2 x)  { union { int i; h2 h; } u; u.h = x; return u.i; }

// EQUAL-WORK STATIC PARTITION (round-13 structure, proven) + CODEGEN-LEAN
// STEP. Fixes round-18's OOB: start = max(lo-WARM, 1) ALWAYS (round 18
// dropped the clamp; lo can be as small as 2 -> start<=0 -> fault).
//
// Warm phase: exactly 8 steps whenever lo>1 (multiple of 4 -> ring stays
// slot-aligned for the main loop). For lo in [2,8], start==1 and the piece
// is evolved exactly from row 0; A_in (t==lo-1) and possibly A_out
// (t==hi-1, short pieces) are captured in-warm via wave-uniform compares.
// Main phase: n = hi - start - warm steps, guard-free x8 blocks + tail;
// A_out measured after the loop iff n>0 (else it fired in-warm, or at
// init for 0-step slen==1 pieces).
//
// Row addressing: rolling 32-bit element offset, wrap (off+64)&65535
// (TT*LL=65536). Wrap stays inside the same sequence's block; wrapped rows
// (only when hi>=1021) are loaded but provably never consumed (a row
// loaded at step t is consumed at step t+4 <= hi-1 only).
//
// Partition: work_b = max(slen_b-1,1), prefix -> meta, K = ceil(W/NWAVES);
// wave wid owns [wid*K,(wid+1)*K) binary-searched into per-seq pieces.
// Piece [lo,hi): delta = A(u@hi-1) - A(u@lo-1) telescopes to log_norm
// (positive transfer operator, Hilbert diam of E=exp(trans) <= 2 ->
// contraction 0.462/step; WARM=8 gave absmax 0.0 rounds 9-17).
// Each piece scores its own unary+binary t-range (lo==1 adds unary(0)).
//
// Step: g = exp2(ring*LOG2E) (row 4 steps old -> off critical path);
// s_j = 32 readlane + 32 fdot2; v = s*g; exact pow-2 renorm on v_0;
// pack via shfl_xor DPP + cvt_pkrtz (no LDS anywhere).

__global__ __launch_bounds__(256) void crf_prefix_kernel(
    const int* __restrict__ seq_lens, int* __restrict__ meta)
{
    __shared__ int sbuf[BB];
    const int tid = threadIdx.x;
    int wv = 0;
    if (tid < BB) { int sl = seq_lens[tid]; wv = (sl > 1) ? (sl - 1) : 1; }
    sbuf[tid] = wv;
    __syncthreads();
    for (int off = 1; off < BB; off <<= 1) {
        int v = (tid >= off) ? sbuf[tid - off] : 0;
        __syncthreads();
        sbuf[tid] += v;
        __syncthreads();
    }
    meta[tid + 1] = sbuf[tid];
    if (tid == 0) {
        meta[0] = 0;
        int W = sbuf[BB - 1];
        meta[BB + 1] = (W + NWAVES - 1) / NWAVES;   // K
    }
}

__global__ __launch_bounds__(256) void crf_piece_kernel(
    const float* __restrict__ logits,    // [B][T][L]
    const int*   __restrict__ labels,    // [B][T]
    const int*   __restrict__ seq_lens,  // [B]
    const float* __restrict__ trans,     // [L][L]
    const int*   __restrict__ meta,      // [258] prefix + K
    float*       __restrict__ part)      // [NWAVES]
{
    const int wid  = blockIdx.x * 4 + (threadIdx.x >> 6);
    const int lane = threadIdx.x & 63;

    // one-time per wave: E-column pairs for this lane's column j = lane
    int ej[32];
    #pragma unroll
    for (int m = 0; m < 32; ++m) {
        float e0 = __builtin_amdgcn_exp2f(trans[(2 * m)     * LL + lane] * LOG2E);
        float e1 = __builtin_amdgcn_exp2f(trans[(2 * m + 1) * LL + lane] * LOG2E);
        ej[m] = h2i(__builtin_amdgcn_cvt_pkrtz(e0, e1));
    }

    const int W = meta[BB];
    const int K = meta[BB + 1];
    int g0 = wid * K;
    int g1 = g0 + K; g1 = (g1 < W) ? g1 : W;

#define RENORM(V) { \
    int eb_ = (__builtin_amdgcn_readfirstlane(__float_as_int(V)) >> 23) & 0xFF; \
    C += eb_ - 127; \
    float scl_ = __int_as_float((254 - eb_) << 23); \
    u = (V) * scl_; \
}
#define PACKD() { \
    float un_ = __shfl_xor(u, 1, 64); \
    upk = h2i(__builtin_amdgcn_cvt_pkrtz(u, un_)); \
}
#define MEAS(OUT) { \
    float us_ = u; \
    _Pragma("unroll") \
    for (int off_ = 32; off_; off_ >>= 1) us_ += __shfl_xor(us_, off_, 64); \
    OUT = ((float)C + __builtin_amdgcn_logf(us_)) * LN2; \
}
// guard-free step on ring slot I with rolling wrapped offset
#define RS(I) { \
    float g_ = __builtin_amdgcn_exp2f(fR##I * LOG2E); \
    fR##I = lg[ldoff]; \
    ldoff = (ldoff + LL) & (TT * LL - 1); \
    float a1_ = 0.f, a2_ = 0.f, a3_ = 0.f, a4_ = 0.f; \
    _Pragma("unroll") \
    for (int m_ = 0; m_ < 32; m_ += 4) { \
        int q0_ = __builtin_amdgcn_readlane(upk, 2 * m_); \
        int q1_ = __builtin_amdgcn_readlane(upk, 2 * m_ + 2); \
        int q2_ = __builtin_amdgcn_readlane(upk, 2 * m_ + 4); \
        int q3_ = __builtin_amdgcn_readlane(upk, 2 * m_ + 6); \
        a1_ = __builtin_amdgcn_fdot2(i2h(q0_), i2h(ej[m_]),     a1_, false); \
        a2_ = __builtin_amdgcn_fdot2(i2h(q1_), i2h(ej[m_ + 1]), a2_, false); \
        a3_ = __builtin_amdgcn_fdot2(i2h(q2_), i2h(ej[m_ + 2]), a3_, false); \
        a4_ = __builtin_amdgcn_fdot2(i2h(q3_), i2h(ej[m_ + 3]), a4_, false); \
    } \
    float v_ = ((a1_ + a2_) + (a3_ + a4_)) * g_; \
    RENORM(v_); \
    PACKD(); \
}
// warm step i (t = start + i): RS + wave-uniform measure hooks
#define WS(I, SLOT) { \
    RS(SLOT); \
    if (start + (I) == lo - 1) MEAS(A_in); \
    if (start + (I) == hi - 1) MEAS(A_out); \
}

    float result = 0.f;
    while (g0 < g1) {
        // binary search: largest b with meta[b] <= g0
        int blo = 0, bhi = BB;
        while (bhi - blo > 1) {
            int mid = (blo + bhi) >> 1;
            if (meta[mid] <= g0) blo = mid; else bhi = mid;
        }
        const int b  = blo;
        const int pe = meta[b + 1];
        const int units = ((g1 < pe) ? g1 : pe) - g0;
        const int lo = g0 - meta[b] + 1;
        const int slen = seq_lens[b];
        const int hi = (lo + units < slen) ? (lo + units) : slen;
        const float* lg  = logits + (size_t)b * TT * LL;
        const int*   lab = labels + b * TT;

        // ---- path-score portion for this piece's t-range ----
        float sc = 0.f;
        for (int t0 = lo + lane; t0 < hi; t0 += 64) {
            int l1 = lab[t0];
            sc += lg[(size_t)t0 * LL + l1] + trans[lab[t0 - 1] * LL + l1];
        }
        if (lo == 1 && lane == 0) sc += lg[lab[0]];   // t = 0 unary
        #pragma unroll
        for (int off = 32; off; off >>= 1) sc += __shfl_xor(sc, off, 64);

        const int start = (lo - WARM > 1) ? (lo - WARM) : 1;   // CLAMPED (r18 bug)
        const int warmN = (lo > 1) ? WARM : 0;
        int C = 0;
        float u;
        int upk;

        // init u = exp(logit[start-1][lane]); exact when start == 1 (row 0)
        u = __builtin_amdgcn_exp2f(lg[lane + (start - 1) * LL] * LOG2E);
        {   // pin u_0 to [1,2) so the renorm invariant holds from the start
            float v0 = u;
            RENORM(v0);
        }
        PACKD();

        // ring preload rows start..start+3 (start+3 <= 1017, in-bounds)
        unsigned ldoff = (unsigned)(lane + start * LL);
        float fR0 = lg[ldoff]; ldoff += LL;
        float fR1 = lg[ldoff]; ldoff += LL;
        float fR2 = lg[ldoff]; ldoff += LL;
        float fR3 = lg[ldoff]; ldoff += LL;   // next load = row start+4

        float A_in = 0.f, A_out = 0.f;

        // ---- warm phase: exactly 8 steps when lo>1 (ring stays aligned) ----
        if (warmN) {
            WS(0, 0); WS(1, 1); WS(2, 2); WS(3, 3);
            WS(4, 0); WS(5, 1); WS(6, 2); WS(7, 3);
        }

        // ---- main phase: n guard-free steps; A_out after, iff n>0 ----
        const int n = hi - start - warmN;
        if (n > 0) {
            for (int r = n >> 3; r > 0; --r) {
                RS(0); RS(1); RS(2); RS(3);
                RS(0); RS(1); RS(2); RS(3);
            }
            const int rem = n & 7;
            if (rem > 0) { RS(0);
            if (rem > 1) { RS(1);
            if (rem > 2) { RS(2);
            if (rem > 3) { RS(3);
            if (rem > 4) { RS(0);
            if (rem > 5) { RS(1);
            if (rem > 6) { RS(2); }}}}}}}
            MEAS(A_out);
        } else if (warmN == 0) {
            MEAS(A_out);   // 0-step piece (slen == 1): logsumexp(logits[0])
        }
        // else: A_out already captured in-warm (short piece, hi-1 <= start+7)

        result += (A_out - A_in) - sc;
        g0 += units;
    }

    if (lane == 0) part[wid] = result;
}

__global__ __launch_bounds__(1024) void reduce_kernel(
    const float* __restrict__ part, float* __restrict__ out)
{
    int tid = threadIdx.x;
    float v = 0.f;
    #pragma unroll
    for (int i = 0; i < 4; ++i) v += part[tid + 1024 * i];
    #pragma unroll
    for (int off = 32; off; off >>= 1) v += __shfl_xor(v, off, 64);
    __shared__ float r[16];
    if ((tid & 63) == 0) r[tid >> 6] = v;
    __syncthreads();
    if (tid == 0) {
        float s = 0.f;
        #pragma unroll
        for (int i = 0; i < 16; ++i) s += r[i];
        out[0] = s;
    }
}

extern "C" void kernel_launch(void* const* d_in, const int* in_sizes, int n_in,
                              void* d_out, int out_size, void* d_ws, size_t ws_size,
                              hipStream_t stream) {
    const float* logits   = (const float*)d_in[0];
    const int*   labels   = (const int*)d_in[1];
    const int*   seq_lens = (const int*)d_in[2];
    const float* trans    = (const float*)d_in[3];

    int*   meta = (int*)d_ws;                         // 258 ints (<4 KB)
    float* part = (float*)((char*)d_ws + 4096);       // NWAVES floats

    crf_prefix_kernel<<<1, 256, 0, stream>>>(seq_lens, meta);
    crf_piece_kernel<<<1024, 256, 0, stream>>>(logits, labels, seq_lens, trans,
                                               meta, part);
    reduce_kernel<<<1, 1024, 0, stream>>>(part, (float*)d_out);
}

// Round 20
// 46.365 us; speedup vs baseline: 1.5101x; 1.0294x over previous
//
#include <hip/hip_runtime.h>

#define TT 1024
#define LL 64
#define BB 256             // batch
#define WARM 4             // warm-up steps (contraction <= 0.462/step; r14: WARM=6 -> absmax 0)
#define NWAVES 4096        // main-kernel waves (1024 blocks x 4)
#define LOG2E 1.44269504088896340736f
#define LN2   0.69314718055994530942f

typedef __fp16 h2 __attribute__((ext_vector_type(2)));
__device__ __forceinline__ h2  i2h(int x) { union { int i; h2 h; } u; u.i = x; return u.h; }
__device__ __forceinline__ int h2i(h2 x)  { union { int i; h2 h; } u; u.h = x; return u.i; }

// EQUAL-WORK STATIC PARTITION (round-19 structure, proven 47.7us total,
// absmax 0.0) with two step changes:
//  * inner product via v_pk_fma_f16 (packed f16 FMA, 4 independent h2
//    accumulators) instead of v_dot2_f32_f16 — tests the hypothesis that
//    dot2 issues at sub-full rate (the unexplained ~2x issue-cycle gap).
//    Same 64 MACs/lane/step; readlane SGPR is the one allowed scalar src.
//  * renorm target [2^-4, 2^-3) (scl bits 250-eb, C += eb-123) so f16
//    accumulation has headroom: 16-term chain <= ~5.6e3, halves-sum
//    <= ~2.2e4 < 65504. A-telescope is invariant to the pin target.
//  * WARM=4 (multiple of 4 keeps the ring slot-aligned; -10% steps).
//
// Partition: work_b = max(slen_b-1,1), prefix -> meta, K = ceil(W/NWAVES);
// wave wid owns [wid*K,(wid+1)*K) binary-searched into per-seq pieces.
// Piece [lo,hi): warm-start max(lo-WARM,1); delta = A(u@hi-1)-A(u@lo-1)
// telescopes to log_norm (positive transfer operator, Hilbert diameter of
// E=exp(trans) <= 2 -> contraction tanh(0.5)=0.462/step). lo==1 exact.
// slen=1: 0-step piece measuring logsumexp(logits[0]) at init.
// Each piece scores its own unary+binary t-range (lo==1 adds unary(0)).
// Warm phase: exactly WARM unguarded steps when lo>1; A_in (t==lo-1) and
// A_out (t==hi-1, short pieces) captured in-warm via wave-uniform compares.
// Main phase: guard-free x8 blocks + tail. Row addressing: rolling 32-bit
// offset, wrap (off+64)&65535 stays in-sequence; wrapped rows never consumed.

__global__ __launch_bounds__(256) void crf_prefix_kernel(
    const int* __restrict__ seq_lens, int* __restrict__ meta)
{
    __shared__ int sbuf[BB];
    const int tid = threadIdx.x;
    int wv = 0;
    if (tid < BB) { int sl = seq_lens[tid]; wv = (sl > 1) ? (sl - 1) : 1; }
    sbuf[tid] = wv;
    __syncthreads();
    for (int off = 1; off < BB; off <<= 1) {
        int v = (tid >= off) ? sbuf[tid - off] : 0;
        __syncthreads();
        sbuf[tid] += v;
        __syncthreads();
    }
    meta[tid + 1] = sbuf[tid];
    if (tid == 0) {
        meta[0] = 0;
        int W = sbuf[BB - 1];
        meta[BB + 1] = (W + NWAVES - 1) / NWAVES;   // K
    }
}

__global__ __launch_bounds__(256) void crf_piece_kernel(
    const float* __restrict__ logits,    // [B][T][L]
    const int*   __restrict__ labels,    // [B][T]
    const int*   __restrict__ seq_lens,  // [B]
    const float* __restrict__ trans,     // [L][L]
    const int*   __restrict__ meta,      // [258] prefix + K
    float*       __restrict__ part)      // [NWAVES]
{
    const int wid  = blockIdx.x * 4 + (threadIdx.x >> 6);
    const int lane = threadIdx.x & 63;

    // one-time per wave: E-column pairs for this lane's column j = lane
    int ej[32];
    #pragma unroll
    for (int m = 0; m < 32; ++m) {
        float e0 = __builtin_amdgcn_exp2f(trans[(2 * m)     * LL + lane] * LOG2E);
        float e1 = __builtin_amdgcn_exp2f(trans[(2 * m + 1) * LL + lane] * LOG2E);
        ej[m] = h2i(__builtin_amdgcn_cvt_pkrtz(e0, e1));
    }

    const int W = meta[BB];
    const int K = meta[BB + 1];
    int g0 = wid * K;
    int g1 = g0 + K; g1 = (g1 < W) ? g1 : W;

// renorm: pin u_0 (lane 0's state) to [2^-4, 2^-3), exact pow-2, C tracks it
#define RENORM(V) { \
    int eb_ = (__builtin_amdgcn_readfirstlane(__float_as_int(V)) >> 23) & 0xFF; \
    C += eb_ - 123; \
    float scl_ = __int_as_float((250 - eb_) << 23); \
    u = (V) * scl_; \
}
#define PACKD() { \
    float un_ = __shfl_xor(u, 1, 64); \
    upk = h2i(__builtin_amdgcn_cvt_pkrtz(u, un_)); \
}
#define MEAS(OUT) { \
    float us_ = u; \
    _Pragma("unroll") \
    for (int off_ = 32; off_; off_ >>= 1) us_ += __shfl_xor(us_, off_, 64); \
    OUT = ((float)C + __builtin_amdgcn_logf(us_)) * LN2; \
}
// guard-free step on ring slot I: packed-f16 FMA inner product
#define RS(I) { \
    float g_ = __builtin_amdgcn_exp2f(fR##I * LOG2E); \
    fR##I = lg[ldoff]; \
    ldoff = (ldoff + LL) & (TT * LL - 1); \
    h2 ac0 = {(__fp16)0.f, (__fp16)0.f}; \
    h2 ac1 = ac0, ac2 = ac0, ac3 = ac0; \
    _Pragma("unroll") \
    for (int m_ = 0; m_ < 32; m_ += 4) { \
        int q0_ = __builtin_amdgcn_readlane(upk, 2 * m_); \
        int q1_ = __builtin_amdgcn_readlane(upk, 2 * m_ + 2); \
        int q2_ = __builtin_amdgcn_readlane(upk, 2 * m_ + 4); \
        int q3_ = __builtin_amdgcn_readlane(upk, 2 * m_ + 6); \
        ac0 += i2h(q0_) * i2h(ej[m_]); \
        ac1 += i2h(q1_) * i2h(ej[m_ + 1]); \
        ac2 += i2h(q2_) * i2h(ej[m_ + 2]); \
        ac3 += i2h(q3_) * i2h(ej[m_ + 3]); \
    } \
    h2 sh_ = (ac0 + ac1) + (ac2 + ac3); \
    float v_ = ((float)sh_[0] + (float)sh_[1]) * g_; \
    RENORM(v_); \
    PACKD(); \
}
// warm step i (t = start + i): RS + wave-uniform measure hooks
#define WS(I, SLOT) { \
    RS(SLOT); \
    if (start + (I) == lo - 1) MEAS(A_in); \
    if (start + (I) == hi - 1) MEAS(A_out); \
}

    float result = 0.f;
    while (g0 < g1) {
        // binary search: largest b with meta[b] <= g0
        int blo = 0, bhi = BB;
        while (bhi - blo > 1) {
            int mid = (blo + bhi) >> 1;
            if (meta[mid] <= g0) blo = mid; else bhi = mid;
        }
        const int b  = blo;
        const int pe = meta[b + 1];
        const int units = ((g1 < pe) ? g1 : pe) - g0;
        const int lo = g0 - meta[b] + 1;
        const int slen = seq_lens[b];
        const int hi = (lo + units < slen) ? (lo + units) : slen;
        const float* lg  = logits + (size_t)b * TT * LL;
        const int*   lab = labels + b * TT;

        // ---- path-score portion for this piece's t-range ----
        float sc = 0.f;
        for (int t0 = lo + lane; t0 < hi; t0 += 64) {
            int l1 = lab[t0];
            sc += lg[(size_t)t0 * LL + l1] + trans[lab[t0 - 1] * LL + l1];
        }
        if (lo == 1 && lane == 0) sc += lg[lab[0]];   // t = 0 unary
        #pragma unroll
        for (int off = 32; off; off >>= 1) sc += __shfl_xor(sc, off, 64);

        const int start = (lo - WARM > 1) ? (lo - WARM) : 1;   // clamped
        const int warmN = (lo > 1) ? WARM : 0;
        int C = 0;
        float u;
        int upk;

        // init u = exp(logit[start-1][lane]); exact when start == 1 (row 0)
        u = __builtin_amdgcn_exp2f(lg[lane + (start - 1) * LL] * LOG2E);
        {   // pin u_0 into [2^-4, 2^-3) so the renorm invariant holds
            float v0 = u;
            RENORM(v0);
        }
        PACKD();

        // ring preload rows start..start+3 (in-bounds: start+3 <= 1017)
        unsigned ldoff = (unsigned)(lane + start * LL);
        float fR0 = lg[ldoff]; ldoff += LL;
        float fR1 = lg[ldoff]; ldoff += LL;
        float fR2 = lg[ldoff]; ldoff += LL;
        float fR3 = lg[ldoff]; ldoff += LL;   // next load = row start+4

        float A_in = 0.f, A_out = 0.f;

        // ---- warm phase: exactly WARM steps when lo>1 (slot-aligned) ----
        if (warmN) {
            WS(0, 0); WS(1, 1); WS(2, 2); WS(3, 3);
        }

        // ---- main phase: n guard-free steps; A_out after, iff n>0 ----
        const int n = hi - start - warmN;
        if (n > 0) {
            for (int r = n >> 3; r > 0; --r) {
                RS(0); RS(1); RS(2); RS(3);
                RS(0); RS(1); RS(2); RS(3);
            }
            const int rem = n & 7;
            if (rem > 0) { RS(0);
            if (rem > 1) { RS(1);
            if (rem > 2) { RS(2);
            if (rem > 3) { RS(3);
            if (rem > 4) { RS(0);
            if (rem > 5) { RS(1);
            if (rem > 6) { RS(2); }}}}}}}
            MEAS(A_out);
        } else if (warmN == 0) {
            MEAS(A_out);   // 0-step piece (slen == 1): logsumexp(logits[0])
        }
        // else: A_out already captured in-warm (short piece)

        result += (A_out - A_in) - sc;
        g0 += units;
    }

    if (lane == 0) part[wid] = result;
}

__global__ __launch_bounds__(1024) void reduce_kernel(
    const float* __restrict__ part, float* __restrict__ out)
{
    int tid = threadIdx.x;
    float v = 0.f;
    #pragma unroll
    for (int i = 0; i < 4; ++i) v += part[tid + 1024 * i];
    #pragma unroll
    for (int off = 32; off; off >>= 1) v += __shfl_xor(v, off, 64);
    __shared__ float r[16];
    if ((tid & 63) == 0) r[tid >> 6] = v;
    __syncthreads();
    if (tid == 0) {
        float s = 0.f;
        #pragma unroll
        for (int i = 0; i < 16; ++i) s += r[i];
        out[0] = s;
    }
}

extern "C" void kernel_launch(void* const* d_in, const int* in_sizes, int n_in,
                              void* d_out, int out_size, void* d_ws, size_t ws_size,
                              hipStream_t stream) {
    const float* logits   = (const float*)d_in[0];
    const int*   labels   = (const int*)d_in[1];
    const int*   seq_lens = (const int*)d_in[2];
    const float* trans    = (const float*)d_in[3];

    int*   meta = (int*)d_ws;                         // 258 ints (<4 KB)
    float* part = (float*)((char*)d_ws + 4096);       // NWAVES floats

    crf_prefix_kernel<<<1, 256, 0, stream>>>(seq_lens, meta);
    crf_piece_kernel<<<1024, 256, 0, stream>>>(logits, labels, seq_lens, trans,
                                               meta, part);
    reduce_kernel<<<1, 1024, 0, stream>>>(part, (float*)d_out);
}

// Round 21
// 41.028 us; speedup vs baseline: 1.7066x; 1.1301x over previous
//
#include <hip/hip_runtime.h>

#define TT 1024
#define LL 64
#define BB 256             // batch
#define WARM 4             // warm-up steps (contraction <= 0.462/step; r20: absmax 0)
#define NWAVES 4096        // main-kernel waves (1024 blocks x 4)
#define LOG2E 1.44269504088896340736f
#define LN2   0.69314718055994530942f

typedef __fp16 h2 __attribute__((ext_vector_type(2)));
typedef int    i4 __attribute__((ext_vector_type(4)));
__device__ __forceinline__ h2  i2h(int x) { union { int i; h2 h; } u; u.i = x; return u.h; }
__device__ __forceinline__ int h2i(h2 x)  { union { int i; h2 h; } u; u.h = x; return u.i; }

// EQUAL-WORK STATIC PARTITION (r19/r20 structure, proven) + LDS-BROADCAST
// GATHER (this round): the 32-deep v_readlane gather (VALU->SGPR->VALU
// hazard chain, suspected 2x issue inflation) is replaced by:
//   * after each pack, even lanes store their pair-word (u_2k,u_2k+1) to a
//     32-word per-wave LDS strip (1 exec-masked ds_write_b32; lanes 0..62
//     even -> banks 0..31, conflict-free);
//   * each step gathers all pairs with 8 ds_read_b128 at a wave-uniform
//     address (same-address -> broadcast, no conflicts). DS ops within a
//     wave are in-order, so write(t-1) -> read(t) needs no barrier.
// fdot2 operands are now VGPR+VGPR (no SGPR on the VALU path).
//
// Everything else identical to the proven kernel: work_b = max(slen_b-1,1),
// prefix -> meta, K = ceil(W/NWAVES); wave wid owns [wid*K,(wid+1)*K)
// binary-searched into per-seq pieces. Piece [lo,hi): warm-start
// max(lo-WARM,1); delta = A(u@hi-1)-A(u@lo-1) telescopes to log_norm
// (positive transfer operator, Hilbert diam of E=exp(trans) <= 2 ->
// contraction 0.462/step). lo==1 exact; slen=1 measures logsumexp(logits[0]).
// Warm = exactly WARM steps when lo>1 with in-warm wave-uniform measure
// hooks; main = guard-free x8 blocks + tail. Row addressing: rolling 32-bit
// offset, wrap (off+64)&65535 stays in-sequence, wrapped rows never consumed.
// Step: g = exp2(ring*LOG2E) (4 steps old, off-chain); s = 32 fdot2;
// v = s*g; exact pow-2 renorm on v_0; pack via shfl_xor DPP + cvt_pkrtz.

__global__ __launch_bounds__(256) void crf_prefix_kernel(
    const int* __restrict__ seq_lens, int* __restrict__ meta)
{
    __shared__ int sbuf[BB];
    const int tid = threadIdx.x;
    int wv = 0;
    if (tid < BB) { int sl = seq_lens[tid]; wv = (sl > 1) ? (sl - 1) : 1; }
    sbuf[tid] = wv;
    __syncthreads();
    for (int off = 1; off < BB; off <<= 1) {
        int v = (tid >= off) ? sbuf[tid - off] : 0;
        __syncthreads();
        sbuf[tid] += v;
        __syncthreads();
    }
    meta[tid + 1] = sbuf[tid];
    if (tid == 0) {
        meta[0] = 0;
        int W = sbuf[BB - 1];
        meta[BB + 1] = (W + NWAVES - 1) / NWAVES;   // K
    }
}

__global__ __launch_bounds__(256) void crf_piece_kernel(
    const float* __restrict__ logits,    // [B][T][L]
    const int*   __restrict__ labels,    // [B][T]
    const int*   __restrict__ seq_lens,  // [B]
    const float* __restrict__ trans,     // [L][L]
    const int*   __restrict__ meta,      // [258] prefix + K
    float*       __restrict__ part)      // [NWAVES]
{
    __shared__ __align__(16) int shq[4][32];   // per-wave pair-word strip
    const int wid  = blockIdx.x * 4 + (threadIdx.x >> 6);
    const int lane = threadIdx.x & 63;
    int* const shb = &shq[threadIdx.x >> 6][0];
    const i4* const shp = (const i4*)shb;

    // one-time per wave: E-column pairs for this lane's column j = lane
    int ej[32];
    #pragma unroll
    for (int m = 0; m < 32; ++m) {
        float e0 = __builtin_amdgcn_exp2f(trans[(2 * m)     * LL + lane] * LOG2E);
        float e1 = __builtin_amdgcn_exp2f(trans[(2 * m + 1) * LL + lane] * LOG2E);
        ej[m] = h2i(__builtin_amdgcn_cvt_pkrtz(e0, e1));
    }

    const int W = meta[BB];
    const int K = meta[BB + 1];
    int g0 = wid * K;
    int g1 = g0 + K; g1 = (g1 < W) ? g1 : W;

#define RENORM(V) { \
    int eb_ = (__builtin_amdgcn_readfirstlane(__float_as_int(V)) >> 23) & 0xFF; \
    C += eb_ - 127; \
    float scl_ = __int_as_float((254 - eb_) << 23); \
    u = (V) * scl_; \
}
// pack + publish: even lane 2k stores pair word (u_2k, u_2k+1) to shb[k]
#define PACKD() { \
    float un_ = __shfl_xor(u, 1, 64); \
    int upk_ = h2i(__builtin_amdgcn_cvt_pkrtz(u, un_)); \
    if (!(lane & 1)) shb[lane >> 1] = upk_; \
}
#define MEAS(OUT) { \
    float us_ = u; \
    _Pragma("unroll") \
    for (int off_ = 32; off_; off_ >>= 1) us_ += __shfl_xor(us_, off_, 64); \
    OUT = ((float)C + __builtin_amdgcn_logf(us_)) * LN2; \
}
// guard-free step on ring slot I: LDS-broadcast gather + 32 fdot2
#define RS(I) { \
    float g_ = __builtin_amdgcn_exp2f(fR##I * LOG2E); \
    fR##I = lg[ldoff]; \
    ldoff = (ldoff + LL) & (TT * LL - 1); \
    i4 w_[8]; \
    _Pragma("unroll") \
    for (int r_ = 0; r_ < 8; ++r_) w_[r_] = shp[r_]; \
    float a1_ = 0.f, a2_ = 0.f, a3_ = 0.f, a4_ = 0.f; \
    _Pragma("unroll") \
    for (int r_ = 0; r_ < 8; ++r_) { \
        a1_ = __builtin_amdgcn_fdot2(i2h(w_[r_][0]), i2h(ej[4 * r_]),     a1_, false); \
        a2_ = __builtin_amdgcn_fdot2(i2h(w_[r_][1]), i2h(ej[4 * r_ + 1]), a2_, false); \
        a3_ = __builtin_amdgcn_fdot2(i2h(w_[r_][2]), i2h(ej[4 * r_ + 2]), a3_, false); \
        a4_ = __builtin_amdgcn_fdot2(i2h(w_[r_][3]), i2h(ej[4 * r_ + 3]), a4_, false); \
    } \
    float v_ = ((a1_ + a2_) + (a3_ + a4_)) * g_; \
    RENORM(v_); \
    PACKD(); \
}
// warm step i (t = start + i): RS + wave-uniform measure hooks
#define WS(I, SLOT) { \
    RS(SLOT); \
    if (start + (I) == lo - 1) MEAS(A_in); \
    if (start + (I) == hi - 1) MEAS(A_out); \
}

    float result = 0.f;
    while (g0 < g1) {
        // binary search: largest b with meta[b] <= g0
        int blo = 0, bhi = BB;
        while (bhi - blo > 1) {
            int mid = (blo + bhi) >> 1;
            if (meta[mid] <= g0) blo = mid; else bhi = mid;
        }
        const int b  = blo;
        const int pe = meta[b + 1];
        const int units = ((g1 < pe) ? g1 : pe) - g0;
        const int lo = g0 - meta[b] + 1;
        const int slen = seq_lens[b];
        const int hi = (lo + units < slen) ? (lo + units) : slen;
        const float* lg  = logits + (size_t)b * TT * LL;
        const int*   lab = labels + b * TT;

        // ---- path-score portion for this piece's t-range ----
        float sc = 0.f;
        for (int t0 = lo + lane; t0 < hi; t0 += 64) {
            int l1 = lab[t0];
            sc += lg[(size_t)t0 * LL + l1] + trans[lab[t0 - 1] * LL + l1];
        }
        if (lo == 1 && lane == 0) sc += lg[lab[0]];   // t = 0 unary
        #pragma unroll
        for (int off = 32; off; off >>= 1) sc += __shfl_xor(sc, off, 64);

        const int start = (lo - WARM > 1) ? (lo - WARM) : 1;   // clamped
        const int warmN = (lo > 1) ? WARM : 0;
        int C = 0;
        float u;

        // init u = exp(logit[start-1][lane]); exact when start == 1 (row 0)
        u = __builtin_amdgcn_exp2f(lg[lane + (start - 1) * LL] * LOG2E);
        {   // pin u_0 to [1,2) so the renorm invariant holds from the start
            float v0 = u;
            RENORM(v0);
        }
        PACKD();

        // ring preload rows start..start+3 (in-bounds: start+3 <= 1017)
        unsigned ldoff = (unsigned)(lane + start * LL);
        float fR0 = lg[ldoff]; ldoff += LL;
        float fR1 = lg[ldoff]; ldoff += LL;
        float fR2 = lg[ldoff]; ldoff += LL;
        float fR3 = lg[ldoff]; ldoff += LL;   // next load = row start+4

        float A_in = 0.f, A_out = 0.f;

        // ---- warm phase: exactly WARM steps when lo>1 (slot-aligned) ----
        if (warmN) {
            WS(0, 0); WS(1, 1); WS(2, 2); WS(3, 3);
        }

        // ---- main phase: n guard-free steps; A_out after, iff n>0 ----
        const int n = hi - start - warmN;
        if (n > 0) {
            for (int r = n >> 3; r > 0; --r) {
                RS(0); RS(1); RS(2); RS(3);
                RS(0); RS(1); RS(2); RS(3);
            }
            const int rem = n & 7;
            if (rem > 0) { RS(0);
            if (rem > 1) { RS(1);
            if (rem > 2) { RS(2);
            if (rem > 3) { RS(3);
            if (rem > 4) { RS(0);
            if (rem > 5) { RS(1);
            if (rem > 6) { RS(2); }}}}}}}
            MEAS(A_out);
        } else if (warmN == 0) {
            MEAS(A_out);   // 0-step piece (slen == 1): logsumexp(logits[0])
        }
        // else: A_out already captured in-warm (short piece)

        result += (A_out - A_in) - sc;
        g0 += units;
    }

    if (lane == 0) part[wid] = result;
}

__global__ __launch_bounds__(1024) void reduce_kernel(
    const float* __restrict__ part, float* __restrict__ out)
{
    int tid = threadIdx.x;
    float v = 0.f;
    #pragma unroll
    for (int i = 0; i < 4; ++i) v += part[tid + 1024 * i];
    #pragma unroll
    for (int off = 32; off; off >>= 1) v += __shfl_xor(v, off, 64);
    __shared__ float r[16];
    if ((tid & 63) == 0) r[tid >> 6] = v;
    __syncthreads();
    if (tid == 0) {
        float s = 0.f;
        #pragma unroll
        for (int i = 0; i < 16; ++i) s += r[i];
        out[0] = s;
    }
}

extern "C" void kernel_launch(void* const* d_in, const int* in_sizes, int n_in,
                              void* d_out, int out_size, void* d_ws, size_t ws_size,
                              hipStream_t stream) {
    const float* logits   = (const float*)d_in[0];
    const int*   labels   = (const int*)d_in[1];
    const int*   seq_lens = (const int*)d_in[2];
    const float* trans    = (const float*)d_in[3];

    int*   meta = (int*)d_ws;                         // 258 ints (<4 KB)
    float* part = (float*)((char*)d_ws + 4096);       // NWAVES floats

    crf_prefix_kernel<<<1, 256, 0, stream>>>(seq_lens, meta);
    crf_piece_kernel<<<1024, 256, 0, stream>>>(logits, labels, seq_lens, trans,
                                               meta, part);
    reduce_kernel<<<1, 1024, 0, stream>>>(part, (float*)d_out);
}

// Round 22
// 40.042 us; speedup vs baseline: 1.7486x; 1.0246x over previous
//
#include <hip/hip_runtime.h>

#define TT 1024
#define LL 64
#define BB 256             // batch
#define WARM 4             // warm-up steps (contraction <= 0.462/step; r20: absmax 0)
#define NWAVES 4096        // main-kernel waves (1024 blocks x 4)
#define LOG2E 1.44269504088896340736f
#define LN2   0.69314718055994530942f

typedef __fp16 h2 __attribute__((ext_vector_type(2)));
typedef int    i4 __attribute__((ext_vector_type(4)));
__device__ __forceinline__ h2  i2h(int x) { union { int i; h2 h; } u; u.i = x; return u.h; }
__device__ __forceinline__ int h2i(h2 x)  { union { int i; h2 h; } u; u.h = x; return u.i; }

// EQUAL-WORK STATIC PARTITION + LDS-BROADCAST GATHER, alias-safe (r22).
// r21 proved the mechanism (replacing the 32-deep v_readlane SGPR-hazard
// gather with 1 ds_write_b32 + 8 broadcast ds_read_b128 = ~11% faster) but
// read the strip through a cast i4* while writing through int* — distinct
// TBAA types, so the compiler could order step t's ds_read before step
// t-1's ds_write -> stale u (absmax 8192). Fixes, nothing else changed:
//  * gather via __builtin_memcpy (char-typed access aliases everything ->
//    write->read program order preserved; still emits ds_read_b128);
//  * asm volatile "" memory fence after the LDS write (compiler-order pin,
//    zero instructions; in-wave DS ops are HW-in-order given program order).
//
// Structure (proven r13-r20): work_b = max(slen_b-1,1), prefix -> meta,
// K = ceil(W/NWAVES); wave wid owns [wid*K,(wid+1)*K) binary-searched into
// per-seq pieces. Piece [lo,hi): warm-start max(lo-WARM,1); delta =
// A(u@hi-1)-A(u@lo-1) telescopes to log_norm (positive transfer operator,
// Hilbert diam of E=exp(trans) <= 2 -> contraction 0.462/step). lo==1
// exact; slen=1 measures logsumexp(logits[0]) at init. Warm = exactly WARM
// steps when lo>1 with in-warm wave-uniform measure hooks; main =
// guard-free x8 blocks + tail. Rows: rolling 32-bit offset, wrap
// (off+64)&65535 stays in-sequence; wrapped rows never consumed.
// Step: g = exp2(ring*LOG2E) (4 steps old, off-chain); s = 32 fdot2 on
// broadcast pair-words; v = s*g; exact pow-2 renorm on v_0; pack via
// shfl_xor DPP + cvt_pkrtz; even lanes publish pair-word to LDS strip.

__global__ __launch_bounds__(256) void crf_prefix_kernel(
    const int* __restrict__ seq_lens, int* __restrict__ meta)
{
    __shared__ int sbuf[BB];
    const int tid = threadIdx.x;
    int wv = 0;
    if (tid < BB) { int sl = seq_lens[tid]; wv = (sl > 1) ? (sl - 1) : 1; }
    sbuf[tid] = wv;
    __syncthreads();
    for (int off = 1; off < BB; off <<= 1) {
        int v = (tid >= off) ? sbuf[tid - off] : 0;
        __syncthreads();
        sbuf[tid] += v;
        __syncthreads();
    }
    meta[tid + 1] = sbuf[tid];
    if (tid == 0) {
        meta[0] = 0;
        int W = sbuf[BB - 1];
        meta[BB + 1] = (W + NWAVES - 1) / NWAVES;   // K
    }
}

__global__ __launch_bounds__(256) void crf_piece_kernel(
    const float* __restrict__ logits,    // [B][T][L]
    const int*   __restrict__ labels,    // [B][T]
    const int*   __restrict__ seq_lens,  // [B]
    const float* __restrict__ trans,     // [L][L]
    const int*   __restrict__ meta,      // [258] prefix + K
    float*       __restrict__ part)      // [NWAVES]
{
    __shared__ __align__(16) int shq[4][32];   // per-wave pair-word strip
    const int wid  = blockIdx.x * 4 + (threadIdx.x >> 6);
    const int lane = threadIdx.x & 63;
    int* const shb = &shq[threadIdx.x >> 6][0];

    // one-time per wave: E-column pairs for this lane's column j = lane
    int ej[32];
    #pragma unroll
    for (int m = 0; m < 32; ++m) {
        float e0 = __builtin_amdgcn_exp2f(trans[(2 * m)     * LL + lane] * LOG2E);
        float e1 = __builtin_amdgcn_exp2f(trans[(2 * m + 1) * LL + lane] * LOG2E);
        ej[m] = h2i(__builtin_amdgcn_cvt_pkrtz(e0, e1));
    }

    const int W = meta[BB];
    const int K = meta[BB + 1];
    int g0 = wid * K;
    int g1 = g0 + K; g1 = (g1 < W) ? g1 : W;

#define RENORM(V) { \
    int eb_ = (__builtin_amdgcn_readfirstlane(__float_as_int(V)) >> 23) & 0xFF; \
    C += eb_ - 127; \
    float scl_ = __int_as_float((254 - eb_) << 23); \
    u = (V) * scl_; \
}
// pack + publish: even lane 2k stores pair word (u_2k, u_2k+1) to shb[k];
// memory fence pins program order of this store vs the next step's reads
#define PACKD() { \
    float un_ = __shfl_xor(u, 1, 64); \
    int upk_ = h2i(__builtin_amdgcn_cvt_pkrtz(u, un_)); \
    if (!(lane & 1)) shb[lane >> 1] = upk_; \
    asm volatile("" ::: "memory"); \
}
#define MEAS(OUT) { \
    float us_ = u; \
    _Pragma("unroll") \
    for (int off_ = 32; off_; off_ >>= 1) us_ += __shfl_xor(us_, off_, 64); \
    OUT = ((float)C + __builtin_amdgcn_logf(us_)) * LN2; \
}
// guard-free step on ring slot I: alias-safe broadcast gather + 32 fdot2
#define RS(I) { \
    float g_ = __builtin_amdgcn_exp2f(fR##I * LOG2E); \
    fR##I = lg[ldoff]; \
    ldoff = (ldoff + LL) & (TT * LL - 1); \
    i4 w_[8]; \
    _Pragma("unroll") \
    for (int r_ = 0; r_ < 8; ++r_) \
        __builtin_memcpy(&w_[r_], shb + 4 * r_, 16); \
    float a1_ = 0.f, a2_ = 0.f, a3_ = 0.f, a4_ = 0.f; \
    _Pragma("unroll") \
    for (int r_ = 0; r_ < 8; ++r_) { \
        a1_ = __builtin_amdgcn_fdot2(i2h(w_[r_][0]), i2h(ej[4 * r_]),     a1_, false); \
        a2_ = __builtin_amdgcn_fdot2(i2h(w_[r_][1]), i2h(ej[4 * r_ + 1]), a2_, false); \
        a3_ = __builtin_amdgcn_fdot2(i2h(w_[r_][2]), i2h(ej[4 * r_ + 2]), a3_, false); \
        a4_ = __builtin_amdgcn_fdot2(i2h(w_[r_][3]), i2h(ej[4 * r_ + 3]), a4_, false); \
    } \
    float v_ = ((a1_ + a2_) + (a3_ + a4_)) * g_; \
    RENORM(v_); \
    PACKD(); \
}
// warm step i (t = start + i): RS + wave-uniform measure hooks
#define WS(I, SLOT) { \
    RS(SLOT); \
    if (start + (I) == lo - 1) MEAS(A_in); \
    if (start + (I) == hi - 1) MEAS(A_out); \
}

    float result = 0.f;
    while (g0 < g1) {
        // binary search: largest b with meta[b] <= g0
        int blo = 0, bhi = BB;
        while (bhi - blo > 1) {
            int mid = (blo + bhi) >> 1;
            if (meta[mid] <= g0) blo = mid; else bhi = mid;
        }
        const int b  = blo;
        const int pe = meta[b + 1];
        const int units = ((g1 < pe) ? g1 : pe) - g0;
        const int lo = g0 - meta[b] + 1;
        const int slen = seq_lens[b];
        const int hi = (lo + units < slen) ? (lo + units) : slen;
        const float* lg  = logits + (size_t)b * TT * LL;
        const int*   lab = labels + b * TT;

        // ---- path-score portion for this piece's t-range ----
        float sc = 0.f;
        for (int t0 = lo + lane; t0 < hi; t0 += 64) {
            int l1 = lab[t0];
            sc += lg[(size_t)t0 * LL + l1] + trans[lab[t0 - 1] * LL + l1];
        }
        if (lo == 1 && lane == 0) sc += lg[lab[0]];   // t = 0 unary
        #pragma unroll
        for (int off = 32; off; off >>= 1) sc += __shfl_xor(sc, off, 64);

        const int start = (lo - WARM > 1) ? (lo - WARM) : 1;   // clamped
        const int warmN = (lo > 1) ? WARM : 0;
        int C = 0;
        float u;

        // init u = exp(logit[start-1][lane]); exact when start == 1 (row 0)
        u = __builtin_amdgcn_exp2f(lg[lane + (start - 1) * LL] * LOG2E);
        {   // pin u_0 to [1,2) so the renorm invariant holds from the start
            float v0 = u;
            RENORM(v0);
        }
        PACKD();

        // ring preload rows start..start+3 (in-bounds: start+3 <= 1017)
        unsigned ldoff = (unsigned)(lane + start * LL);
        float fR0 = lg[ldoff]; ldoff += LL;
        float fR1 = lg[ldoff]; ldoff += LL;
        float fR2 = lg[ldoff]; ldoff += LL;
        float fR3 = lg[ldoff]; ldoff += LL;   // next load = row start+4

        float A_in = 0.f, A_out = 0.f;

        // ---- warm phase: exactly WARM steps when lo>1 (slot-aligned) ----
        if (warmN) {
            WS(0, 0); WS(1, 1); WS(2, 2); WS(3, 3);
        }

        // ---- main phase: n guard-free steps; A_out after, iff n>0 ----
        const int n = hi - start - warmN;
        if (n > 0) {
            for (int r = n >> 3; r > 0; --r) {
                RS(0); RS(1); RS(2); RS(3);
                RS(0); RS(1); RS(2); RS(3);
            }
            const int rem = n & 7;
            if (rem > 0) { RS(0);
            if (rem > 1) { RS(1);
            if (rem > 2) { RS(2);
            if (rem > 3) { RS(3);
            if (rem > 4) { RS(0);
            if (rem > 5) { RS(1);
            if (rem > 6) { RS(2); }}}}}}}
            MEAS(A_out);
        } else if (warmN == 0) {
            MEAS(A_out);   // 0-step piece (slen == 1): logsumexp(logits[0])
        }
        // else: A_out already captured in-warm (short piece)

        result += (A_out - A_in) - sc;
        g0 += units;
    }

    if (lane == 0) part[wid] = result;
}

__global__ __launch_bounds__(1024) void reduce_kernel(
    const float* __restrict__ part, float* __restrict__ out)
{
    int tid = threadIdx.x;
    float v = 0.f;
    #pragma unroll
    for (int i = 0; i < 4; ++i) v += part[tid + 1024 * i];
    #pragma unroll
    for (int off = 32; off; off >>= 1) v += __shfl_xor(v, off, 64);
    __shared__ float r[16];
    if ((tid & 63) == 0) r[tid >> 6] = v;
    __syncthreads();
    if (tid == 0) {
        float s = 0.f;
        #pragma unroll
        for (int i = 0; i < 16; ++i) s += r[i];
        out[0] = s;
    }
}

extern "C" void kernel_launch(void* const* d_in, const int* in_sizes, int n_in,
                              void* d_out, int out_size, void* d_ws, size_t ws_size,
                              hipStream_t stream) {
    const float* logits   = (const float*)d_in[0];
    const int*   labels   = (const int*)d_in[1];
    const int*   seq_lens = (const int*)d_in[2];
    const float* trans    = (const float*)d_in[3];

    int*   meta = (int*)d_ws;                         // 258 ints (<4 KB)
    float* part = (float*)((char*)d_ws + 4096);       // NWAVES floats

    crf_prefix_kernel<<<1, 256, 0, stream>>>(seq_lens, meta);
    crf_piece_kernel<<<1024, 256, 0, stream>>>(logits, labels, seq_lens, trans,
                                               meta, part);
    reduce_kernel<<<1, 1024, 0, stream>>>(part, (float*)d_out);
}